// Round 5
// baseline (426.706 us; speedup 1.0000x reference)
//
#include <hip/hip_runtime.h>
#include <math.h>

// Problem constants (from reference)
#define NN 50000
#define NE 800000
#define NFEAT 128
#define NHID 64
#define NCLASS 16
#define NB_SCAN ((NN + 255) / 256)  // 196
#define ROWS_PER_GRP 6250           // NN / 8 XCD groups
#define SCHUNKS 392                 // scatter edge chunks; grid = 8*392
#define HIST_BLOCKS ((NE + 255) / 256)  // 3125
#define GB ((NN + 63) / 64)             // 782 row-tiles

struct alignas(8) Edge {
    int c;
    float w;
};

// fp32 <-> bf16 helpers (RNE round)
__device__ inline unsigned short f2bf(float f) {
    unsigned u = __builtin_bit_cast(unsigned, f);
    u += 0x7fffu + ((u >> 16) & 1u);
    return (unsigned short)(u >> 16);
}
__device__ inline float bf2f(unsigned short h) {
    return __builtin_bit_cast(float, (unsigned)h << 16);
}

// ---------------- CSR build ----------------

__global__ __launch_bounds__(256) void scan_sum_kernel(const int* __restrict__ deg,
                                                       int* __restrict__ blocksum, int n) {
    __shared__ int s[256];
    const int t = threadIdx.x;
    int i = blockIdx.x * 256 + t;
    s[t] = (i < n) ? deg[i] : 0;
    __syncthreads();
#pragma unroll
    for (int off = 128; off > 0; off >>= 1) {
        if (t < off) s[t] += s[t + off];
        __syncthreads();
    }
    if (t == 0) blocksum[blockIdx.x] = s[0];
}

__global__ __launch_bounds__(256) void scan_top_kernel(int* __restrict__ blocksum, int nb) {
    __shared__ int s[256];
    const int t = threadIdx.x;
    int v = (t < nb) ? blocksum[t] : 0;
    s[t] = v;
    __syncthreads();
    for (int off = 1; off < 256; off <<= 1) {
        int u = (t >= off) ? s[t - off] : 0;
        __syncthreads();
        s[t] += u;
        __syncthreads();
    }
    if (t < nb) blocksum[t] = s[t] - v;  // exclusive
}

__global__ __launch_bounds__(256) void scan_final_kernel(const int* __restrict__ deg,
                                                         const int* __restrict__ blocksum,
                                                         int* __restrict__ row_ptr,
                                                         int* __restrict__ cursor, int n) {
    __shared__ int s[256];
    const int t = threadIdx.x;
    int i = blockIdx.x * 256 + t;
    int d = (i < n) ? deg[i] : 0;
    s[t] = d;
    __syncthreads();
    for (int off = 1; off < 256; off <<= 1) {
        int u = (t >= off) ? s[t - off] : 0;
        __syncthreads();
        s[t] += u;
        __syncthreads();
    }
    int excl = blocksum[blockIdx.x] + s[t] - d;
    if (i < n) {
        row_ptr[i] = excl;
        cursor[i] = excl;
        if (i == n - 1) row_ptr[n] = excl + d;
    }
}

// XCD-partitioned scatter (see round 3): block b -> row group b%8, edge chunk b/8.
__global__ __launch_bounds__(256) void scatter_part_kernel(const int* __restrict__ row,
                                                           const int* __restrict__ col,
                                                           const float* __restrict__ w,
                                                           int* __restrict__ cursor,
                                                           Edge* __restrict__ pairs, int E) {
    const int g = blockIdx.x & 7;
    const int chunk = blockIdx.x >> 3;
    const int CH = (E + SCHUNKS - 1) / SCHUNKS;
    const int lo = chunk * CH;
    const int hi = (lo + CH < E) ? lo + CH : E;
    for (int e = lo + threadIdx.x; e < hi; e += 256) {
        int r = row[e];
        if (r / ROWS_PER_GRP == g) {
            int pos = atomicAdd(&cursor[r], 1);
            Edge p;
            p.c = col[e];
            p.w = w[e];
            pairs[pos] = p;
        }
    }
}

// ---------------- Merged: hist (CSR degree) + gemm1 (x @ W1 -> bf16 tmpbA) ----------------
// Blocks [0,HIST_BLOCKS): histogram. Blocks [HIST_BLOCKS, HIST_BLOCKS+GB): 64x64-tile GEMM,
// K=128, bf16 output. Independent work overlapped in one dispatch.
__global__ __launch_bounds__(256) void hist_gemm1_kernel(const int* __restrict__ erow,
                                                         int* __restrict__ deg,
                                                         const float* __restrict__ in,
                                                         const float* __restrict__ Wg,
                                                         unsigned short* __restrict__ outb,
                                                         int M) {
    __shared__ float xs[64][68];
    __shared__ float Ws[64][64];
    if (blockIdx.x < HIST_BLOCKS) {
        int e = blockIdx.x * 256 + threadIdx.x;
        if (e < NE) atomicAdd(&deg[erow[e]], 1);
        return;
    }
    constexpr int K = NFEAT;
    const int t = threadIdx.x;
    const int tx = t % 16;
    const int ty = t / 16;
    const int r0 = (blockIdx.x - HIST_BLOCKS) * 64;

    float acc[4][4];
#pragma unroll
    for (int i = 0; i < 4; i++)
#pragma unroll
        for (int j = 0; j < 4; j++) acc[i][j] = 0.f;

    for (int k0 = 0; k0 < K; k0 += 64) {
        for (int i = t * 4; i < 64 * 64; i += 1024) {
            *(float4*)&Ws[i / 64][i % 64] = *(const float4*)&Wg[(size_t)k0 * 64 + i];
        }
        {
            const int r = t / 4;
            const int q = t % 4;
            const int gr = r0 + r;
#pragma unroll
            for (int i = 0; i < 4; i++) {
                int k = q * 16 + i * 4;
                float4 v;
                if (gr < M)
                    v = *(const float4*)&in[(size_t)gr * K + k0 + k];
                else
                    v = make_float4(0.f, 0.f, 0.f, 0.f);
                xs[k + 0][r] = v.x;
                xs[k + 1][r] = v.y;
                xs[k + 2][r] = v.z;
                xs[k + 3][r] = v.w;
            }
        }
        __syncthreads();
#pragma unroll 8
        for (int k = 0; k < 64; k++) {
            float4 xv = *(const float4*)&xs[k][ty * 4];
            float4 wv = *(const float4*)&Ws[k][tx * 4];
            acc[0][0] += xv.x * wv.x; acc[0][1] += xv.x * wv.y;
            acc[0][2] += xv.x * wv.z; acc[0][3] += xv.x * wv.w;
            acc[1][0] += xv.y * wv.x; acc[1][1] += xv.y * wv.y;
            acc[1][2] += xv.y * wv.z; acc[1][3] += xv.y * wv.w;
            acc[2][0] += xv.z * wv.x; acc[2][1] += xv.z * wv.y;
            acc[2][2] += xv.z * wv.z; acc[2][3] += xv.z * wv.w;
            acc[3][0] += xv.w * wv.x; acc[3][1] += xv.w * wv.y;
            acc[3][2] += xv.w * wv.z; acc[3][3] += xv.w * wv.w;
        }
        __syncthreads();
    }
#pragma unroll
    for (int i = 0; i < 4; i++) {
        int r = r0 + ty * 4 + i;
        if (r < M) {
            ushort4 u;
            u.x = f2bf(acc[i][0]);
            u.y = f2bf(acc[i][1]);
            u.z = f2bf(acc[i][2]);
            u.w = f2bf(acc[i][3]);
            *(ushort4*)&outb[(size_t)r * 64 + tx * 4] = u;
        }
    }
}

// ---------------- Fused layer: spmm(tmpb_in)+bias -> e_out(global) ; relu -> LDS h-tile ;
//                  h-tile @ W -> next_out (bf16 [M,64] if NOUT==64, fp32 [M,16] if NOUT==16)
// Block = 64 rows. Phase 1: 4 waves x 16 rows, lane = feature, gather unroll-8.
// Phase 2: register-tiled GEMM from LDS.
template <int NOUT>
__global__ __launch_bounds__(256) void fused_layer_kernel(
    const unsigned short* __restrict__ tmpb_in, const int* __restrict__ row_ptr,
    const Edge* __restrict__ pairs, const float* __restrict__ bias,
    const float* __restrict__ Wg, float* __restrict__ e_out, void* __restrict__ next_out,
    int M) {
    __shared__ float hs[64][66];          // [local row][k], stride 66: phase-2 reads conflict-free
    __shared__ float Ws[64 * NOUT];
    const int t = threadIdx.x;
    for (int i = t * 4; i < 64 * NOUT; i += 1024) {
        *(float4*)&Ws[i] = *(const float4*)&Wg[i];
    }

    const int lane = t & 63;
    const int wave = t >> 6;
    const int r0 = blockIdx.x * 64;
    const float bv = bias[lane];

    // Phase 1: SpMM rows r0..r0+63 (wave w -> rows w*16..w*16+15)
    for (int i = 0; i < 16; i++) {
        const int lr = wave * 16 + i;
        const int r = r0 + lr;
        if (r < M) {
            const int start = __builtin_amdgcn_readfirstlane(row_ptr[r]);
            const int end = __builtin_amdgcn_readfirstlane(row_ptr[r + 1]);
            float acc = 0.f;
            int e = start;
            for (; e + 7 < end; e += 8) {
                Edge p0 = pairs[e + 0], p1 = pairs[e + 1], p2 = pairs[e + 2], p3 = pairs[e + 3];
                Edge p4 = pairs[e + 4], p5 = pairs[e + 5], p6 = pairs[e + 6], p7 = pairs[e + 7];
                float g0 = bf2f(tmpb_in[(size_t)p0.c * 64 + lane]);
                float g1 = bf2f(tmpb_in[(size_t)p1.c * 64 + lane]);
                float g2 = bf2f(tmpb_in[(size_t)p2.c * 64 + lane]);
                float g3 = bf2f(tmpb_in[(size_t)p3.c * 64 + lane]);
                float g4 = bf2f(tmpb_in[(size_t)p4.c * 64 + lane]);
                float g5 = bf2f(tmpb_in[(size_t)p5.c * 64 + lane]);
                float g6 = bf2f(tmpb_in[(size_t)p6.c * 64 + lane]);
                float g7 = bf2f(tmpb_in[(size_t)p7.c * 64 + lane]);
                acc += p0.w * g0; acc += p1.w * g1; acc += p2.w * g2; acc += p3.w * g3;
                acc += p4.w * g4; acc += p5.w * g5; acc += p6.w * g6; acc += p7.w * g7;
            }
            for (; e < end; e++) {
                Edge p = pairs[e];
                acc += p.w * bf2f(tmpb_in[(size_t)p.c * 64 + lane]);
            }
            float v = acc + bv;
            e_out[(size_t)r * 64 + lane] = v;
            hs[lr][lane] = fmaxf(v, 0.f);
        } else {
            hs[lr][lane] = 0.f;
        }
    }
    __syncthreads();

    // Phase 2: h-tile @ W
    if (NOUT == 64) {
        const int tx = t % 16;
        const int ty = t / 16;
        float acc2[4][4];
#pragma unroll
        for (int i = 0; i < 4; i++)
#pragma unroll
            for (int j = 0; j < 4; j++) acc2[i][j] = 0.f;
#pragma unroll 4
        for (int k = 0; k < 64; k++) {
            float4 wv = *(const float4*)&Ws[k * 64 + tx * 4];
            float h0 = hs[ty * 4 + 0][k];
            float h1 = hs[ty * 4 + 1][k];
            float h2 = hs[ty * 4 + 2][k];
            float h3 = hs[ty * 4 + 3][k];
            acc2[0][0] += h0 * wv.x; acc2[0][1] += h0 * wv.y;
            acc2[0][2] += h0 * wv.z; acc2[0][3] += h0 * wv.w;
            acc2[1][0] += h1 * wv.x; acc2[1][1] += h1 * wv.y;
            acc2[1][2] += h1 * wv.z; acc2[1][3] += h1 * wv.w;
            acc2[2][0] += h2 * wv.x; acc2[2][1] += h2 * wv.y;
            acc2[2][2] += h2 * wv.z; acc2[2][3] += h2 * wv.w;
            acc2[3][0] += h3 * wv.x; acc2[3][1] += h3 * wv.y;
            acc2[3][2] += h3 * wv.z; acc2[3][3] += h3 * wv.w;
        }
        unsigned short* ob = (unsigned short*)next_out;
#pragma unroll
        for (int i = 0; i < 4; i++) {
            int r = r0 + ty * 4 + i;
            if (r < M) {
                ushort4 u;
                u.x = f2bf(acc2[i][0]);
                u.y = f2bf(acc2[i][1]);
                u.z = f2bf(acc2[i][2]);
                u.w = f2bf(acc2[i][3]);
                *(ushort4*)&ob[(size_t)r * 64 + tx * 4] = u;
            }
        }
    } else {  // NOUT == 16, fp32 output
        const int tx = t % 4;
        const int ty = t / 4;  // local row
        float a0 = 0.f, a1 = 0.f, a2 = 0.f, a3 = 0.f;
#pragma unroll 4
        for (int k = 0; k < 64; k++) {
            float4 wv = *(const float4*)&Ws[k * 16 + tx * 4];
            float h = hs[ty][k];
            a0 += h * wv.x;
            a1 += h * wv.y;
            a2 += h * wv.z;
            a3 += h * wv.w;
        }
        int r = r0 + ty;
        if (r < M) {
            float4 v;
            v.x = a0; v.y = a1; v.z = a2; v.w = a3;
            *(float4*)&((float*)next_out)[(size_t)r * 16 + tx * 4] = v;
        }
    }
}

// ---------------- SpMM (F=16, fp32) fused with log_softmax ----------------
__global__ __launch_bounds__(256) void spmm16_lsm_kernel(const float* __restrict__ tmp,
                                                         const int* __restrict__ row_ptr,
                                                         const Edge* __restrict__ pairs,
                                                         const float* __restrict__ bias,
                                                         float* __restrict__ e5,
                                                         float* __restrict__ out0, int M) {
    const int f = threadIdx.x & 15;
    const int rl = threadIdx.x >> 4;
    const int r = blockIdx.x * 16 + rl;
    if (r >= M) return;

    const int start = row_ptr[r];
    const int end = row_ptr[r + 1];
    float acc = 0.f;
    int e = start;
    for (; e + 7 < end; e += 8) {
        Edge p0 = pairs[e + 0], p1 = pairs[e + 1], p2 = pairs[e + 2], p3 = pairs[e + 3];
        Edge p4 = pairs[e + 4], p5 = pairs[e + 5], p6 = pairs[e + 6], p7 = pairs[e + 7];
        acc += p0.w * tmp[(size_t)p0.c * 16 + f];
        acc += p1.w * tmp[(size_t)p1.c * 16 + f];
        acc += p2.w * tmp[(size_t)p2.c * 16 + f];
        acc += p3.w * tmp[(size_t)p3.c * 16 + f];
        acc += p4.w * tmp[(size_t)p4.c * 16 + f];
        acc += p5.w * tmp[(size_t)p5.c * 16 + f];
        acc += p6.w * tmp[(size_t)p6.c * 16 + f];
        acc += p7.w * tmp[(size_t)p7.c * 16 + f];
    }
    for (; e < end; e++) {
        Edge p = pairs[e];
        acc += p.w * tmp[(size_t)p.c * 16 + f];
    }
    float v = acc + bias[f];
    e5[(size_t)r * 16 + f] = v;

    float m = v;
#pragma unroll
    for (int off = 1; off < 16; off <<= 1) m = fmaxf(m, __shfl_xor(m, off, 16));
    float s = expf(v - m);
#pragma unroll
    for (int off = 1; off < 16; off <<= 1) s += __shfl_xor(s, off, 16);
    float ls = logf(s);
    out0[(size_t)r * 16 + f] = v - m - ls;
}

// ---------------- launch ----------------

extern "C" void kernel_launch(void* const* d_in, const int* in_sizes, int n_in,
                              void* d_out, int out_size, void* d_ws, size_t ws_size,
                              hipStream_t stream) {
    const float* x = (const float*)d_in[0];
    const int* erow = (const int*)d_in[1];
    const int* ecol = (const int*)d_in[2];
    const float* ew = (const float*)d_in[3];
    const float* W1 = (const float*)d_in[4];
    const float* b1 = (const float*)d_in[5];
    const float* W2 = (const float*)d_in[6];
    const float* b2 = (const float*)d_in[7];
    const float* W3 = (const float*)d_in[8];
    const float* b3 = (const float*)d_in[9];
    const float* W4 = (const float*)d_in[10];
    const float* b4 = (const float*)d_in[11];
    const float* W5 = (const float*)d_in[12];
    const float* b5 = (const float*)d_in[13];

    // Output layout: log_softmax(e5), e1, e2, e3, e4, e5
    float* out0 = (float*)d_out;
    float* e1 = out0 + (size_t)NN * NCLASS;
    float* e2 = e1 + (size_t)NN * NHID;
    float* e3 = e2 + (size_t)NN * NHID;
    float* e4 = e3 + (size_t)NN * NHID;
    float* e5 = e4 + (size_t)NN * NHID;

    // Workspace layout
    char* ws = (char*)d_ws;
    unsigned short* tmpbA = (unsigned short*)ws; ws += (size_t)NN * NHID * 2;  // 6.4 MB
    unsigned short* tmpbB = (unsigned short*)ws; ws += (size_t)NN * NHID * 2;  // 6.4 MB
    float* tmp32 = (float*)ws; ws += (size_t)NN * NCLASS * sizeof(float);      // 3.2 MB
    int* deg = (int*)ws;       ws += ((size_t)NN * 4 + 255) / 256 * 256;
    int* row_ptr = (int*)ws;   ws += ((size_t)(NN + 1) * 4 + 255) / 256 * 256;
    int* cursor = (int*)ws;    ws += ((size_t)NN * 4 + 255) / 256 * 256;
    int* blocksum = (int*)ws;  ws += ((size_t)NB_SCAN * 4 + 255) / 256 * 256;
    Edge* pairs = (Edge*)ws;   ws += (size_t)NE * sizeof(Edge);                // 6.4 MB

    // ---- CSR build overlapped with layer-1 GEMM ----
    hipMemsetAsync(deg, 0, (size_t)NN * sizeof(int), stream);
    hist_gemm1_kernel<<<HIST_BLOCKS + GB, 256, 0, stream>>>(erow, deg, x, W1, tmpbA, NN);
    scan_sum_kernel<<<NB_SCAN, 256, 0, stream>>>(deg, blocksum, NN);
    scan_top_kernel<<<1, 256, 0, stream>>>(blocksum, NB_SCAN);
    scan_final_kernel<<<NB_SCAN, 256, 0, stream>>>(deg, blocksum, row_ptr, cursor, NN);
    scatter_part_kernel<<<8 * SCHUNKS, 256, 0, stream>>>(erow, ecol, ew, cursor, pairs, NE);

    // ---- Fused layers: spmm_k (+bias, e_k out, relu) + gemm_{k+1} ----
    fused_layer_kernel<64><<<GB, 256, 0, stream>>>(tmpbA, row_ptr, pairs, b1, W2, e1, tmpbB, NN);
    fused_layer_kernel<64><<<GB, 256, 0, stream>>>(tmpbB, row_ptr, pairs, b2, W3, e2, tmpbA, NN);
    fused_layer_kernel<64><<<GB, 256, 0, stream>>>(tmpbA, row_ptr, pairs, b3, W4, e3, tmpbB, NN);
    fused_layer_kernel<16><<<GB, 256, 0, stream>>>(tmpbB, row_ptr, pairs, b4, W5, e4, tmp32, NN);

    // ---- Layer 5 SpMM fused with log_softmax ----
    spmm16_lsm_kernel<<<(NN + 15) / 16, 256, 0, stream>>>(tmp32, row_ptr, pairs, b5, e5, out0, NN);
}